// Round 16
// baseline (2947.496 us; speedup 1.0000x reference)
//
#include <hip/hip_runtime.h>
#include <cstdint>
#include <cstddef>

typedef __attribute__((ext_vector_type(4))) float f32x4;
typedef __attribute__((ext_vector_type(8))) short s16x8;
typedef __attribute__((ext_vector_type(4))) unsigned short u16x4;
typedef __attribute__((ext_vector_type(2))) unsigned short u16x2;

#define NLAYER 8
#define DM 1024
#define NTOK 4096
#define DFF2 4096
#define NV 50257

__device__ __forceinline__ unsigned short f2bf(float f) {
  unsigned int u = __float_as_uint(f);
  u = u + 0x7fffu + ((u >> 16) & 1u);
  return (unsigned short)(u >> 16);
}

// CK-style generic->AS1/AS3 conversion for global_load_lds (width 16B).
__device__ __forceinline__ void gload_lds16(const void* gp, void* lp) {
  const __attribute__((address_space(1))) unsigned int* g =
      reinterpret_cast<const __attribute__((address_space(1))) unsigned int*>(
          reinterpret_cast<uintptr_t>(gp));
  __attribute__((address_space(3))) unsigned int* l =
      reinterpret_cast<__attribute__((address_space(3))) unsigned int*>(
          (unsigned int)(uintptr_t)lp);
  __builtin_amdgcn_global_load_lds(g, l, 16, 0, 0);
}

// ---------------- weight convert + transpose: out[n][k] = bf16(in[k][n]) ----
__global__ void __launch_bounds__(256) convT_k(const float* __restrict__ in,
                                               unsigned short* __restrict__ out,
                                               int K, int N, size_t zStride) {
  __shared__ float tile[64][65];
  const int n0 = blockIdx.x * 64, k0 = blockIdx.y * 64;
  const float* inp = in + (size_t)blockIdx.z * K * N;
  unsigned short* outp = out + (size_t)blockIdx.z * zStride;
  const int tid = threadIdx.x;
#pragma unroll
  for (int p = 0; p < 16; ++p) {
    const int r = p * 4 + (tid >> 6);
    const int cc = tid & 63;
    const int gn = n0 + cc;
    tile[r][cc] = (gn < N) ? inp[(size_t)(k0 + r) * N + gn] : 0.f;
  }
  __syncthreads();
#pragma unroll
  for (int p = 0; p < 8; ++p) {
    const int lin = p * 256 + tid;
    const int rn = lin >> 5;
    const int c2 = (lin & 31) * 2;
    u16x2 o;
    o[0] = f2bf(tile[c2][rn]);
    o[1] = f2bf(tile[c2 + 1][rn]);
    *(u16x2*)&outp[(size_t)(n0 + rn) * K + k0 + c2] = o;
  }
}

// ---------------- embedding: x = wte[idx] + wpe[t] ----------------
__global__ void __launch_bounds__(256) embed_k(const int* __restrict__ idx,
                                               const float* __restrict__ wte,
                                               const float* __restrict__ wpe,
                                               float* __restrict__ X) {
  const int tok = blockIdx.x;
  const int t = tok & 1023;
  const int id = idx[tok];
  const int c = threadIdx.x * 4;
  f32x4 a = *(const f32x4*)&wte[(size_t)id * DM + c];
  f32x4 p = *(const f32x4*)&wpe[(size_t)t * DM + c];
  a = a + p;
  *(f32x4*)&X[(size_t)tok * DM + c] = a;
}

// ---------------- LayerNorm: f32 in -> bf16 out ----------------
__global__ void __launch_bounds__(256) ln_k(const float* __restrict__ X,
                                            const float* __restrict__ W,
                                            const float* __restrict__ Bp,
                                            unsigned short* __restrict__ O) {
  const int row = blockIdx.x, tid = threadIdx.x;
  const size_t base = (size_t)row * DM;
  f32x4 v = *(const f32x4*)&X[base + tid * 4];
  float s = v[0] + v[1] + v[2] + v[3];
  float q = v[0] * v[0] + v[1] * v[1] + v[2] * v[2] + v[3] * v[3];
#pragma unroll
  for (int m = 1; m < 64; m <<= 1) {
    s += __shfl_xor(s, m);
    q += __shfl_xor(q, m);
  }
  __shared__ float ps[4], pq[4];
  const int wv = tid >> 6;
  if ((tid & 63) == 0) { ps[wv] = s; pq[wv] = q; }
  __syncthreads();
  s = ps[0] + ps[1] + ps[2] + ps[3];
  q = pq[0] + pq[1] + pq[2] + pq[3];
  const float mu = s * (1.f / DM);
  const float var = q * (1.f / DM) - mu * mu;
  const float rstd = rsqrtf(var + 1e-5f);
  f32x4 w = *(const f32x4*)&W[tid * 4];
  f32x4 bb = *(const f32x4*)&Bp[tid * 4];
  u16x4 o;
#pragma unroll
  for (int j = 0; j < 4; ++j) o[j] = f2bf((v[j] - mu) * rstd * w[j] + bb[j]);
  *(u16x4*)&O[base + tid * 4] = o;
}

// -------- fused: X += bias + P0 + P1; then LN(X) -> bf16 O --------
__global__ void __launch_bounds__(256) reduce2ln_k(
    float* __restrict__ X, const float* __restrict__ bias,
    const float* __restrict__ P0, const float* __restrict__ P1,
    const float* __restrict__ W, const float* __restrict__ Bp,
    unsigned short* __restrict__ O) {
  const int row = blockIdx.x, tid = threadIdx.x;
  const size_t base = (size_t)row * DM;
  const size_t i = base + tid * 4;
  f32x4 v = *(f32x4*)&X[i];
  {
    f32x4 b = *(const f32x4*)&bias[tid * 4];
    f32x4 a = *(const f32x4*)&P0[i];
    f32x4 c = *(const f32x4*)&P1[i];
    v = v + b + a + c;
    *(f32x4*)&X[i] = v;
  }
  float s = v[0] + v[1] + v[2] + v[3];
  float q = v[0] * v[0] + v[1] * v[1] + v[2] * v[2] + v[3] * v[3];
#pragma unroll
  for (int m = 1; m < 64; m <<= 1) {
    s += __shfl_xor(s, m);
    q += __shfl_xor(q, m);
  }
  __shared__ float ps[4], pq[4];
  const int wv = tid >> 6;
  if ((tid & 63) == 0) { ps[wv] = s; pq[wv] = q; }
  __syncthreads();
  s = ps[0] + ps[1] + ps[2] + ps[3];
  q = pq[0] + pq[1] + pq[2] + pq[3];
  const float mu = s * (1.f / DM);
  const float var = q * (1.f / DM) - mu * mu;
  const float rstd = rsqrtf(var + 1e-5f);
  f32x4 w = *(const f32x4*)&W[tid * 4];
  f32x4 bb = *(const f32x4*)&Bp[tid * 4];
  u16x4 o;
#pragma unroll
  for (int j = 0; j < 4; ++j) o[j] = f2bf((v[j] - mu) * rstd * w[j] + bb[j]);
  *(u16x4*)&O[base + tid * 4] = o;
}

// ---------------- GEMM 128x128 (m97 structure, BK=64, XOR-swizzled LDS) ----
__global__ void __launch_bounds__(256) gemm_k(
    const unsigned short* __restrict__ A, const unsigned short* __restrict__ Bt,
    const float* __restrict__ bias, float* __restrict__ outF,
    unsigned short* __restrict__ outB, int M, int N, int K, int lda, int ldc) {
  __shared__ __align__(16) unsigned short lA[128 * 64];
  __shared__ __align__(16) unsigned short lB[128 * 64];
  const int tid = threadIdx.x;
  const int wv = tid >> 6, lane = tid & 63;
  const int row0 = blockIdx.y * 128, col0 = blockIdx.x * 128;
  const int wr = wv >> 1, wc = wv & 1;

  const int z = blockIdx.z;
  A += (size_t)z * K;
  Bt += (size_t)z * K;
  if (gridDim.z > 1) outF += (size_t)z * M * ldc;

  f32x4 acc[4][4] = {};

  const int sRow = tid >> 3;                              // 0..31
  const int sColSw = ((tid & 7) * 8) ^ ((sRow & 7) * 8);  // elements, [0,64)
  const unsigned short* gA = A + (size_t)(row0 + sRow) * lda + sColSw;
  const unsigned short* gB = Bt + (size_t)(col0 + sRow) * lda + sColSw;
  unsigned short* lAd = lA + tid * 8;
  unsigned short* lBd = lB + tid * 8;
  const size_t step32 = (size_t)32 * lda;

  const int rbase = lane & 15;
  const int kHi = (lane >> 4) * 8;
  const int kSw = (lane & 7) * 8;

  for (int kt = 0; kt < K; kt += 64) {
#pragma unroll
    for (int i = 0; i < 4; ++i) {
      gload_lds16(gA + kt + i * step32, lAd + i * 2048);
      gload_lds16(gB + kt + i * step32, lBd + i * 2048);
    }
    __syncthreads();
    s16x8 af[2][4], bfr[2][4];
#pragma unroll
    for (int kk = 0; kk < 2; ++kk) {
      const int kph = (kk * 32 + kHi) ^ kSw;
#pragma unroll
      for (int m = 0; m < 4; ++m)
        af[kk][m] = *(const s16x8*)&lA[(wr * 64 + m * 16 + rbase) * 64 + kph];
#pragma unroll
      for (int n = 0; n < 4; ++n)
        bfr[kk][n] = *(const s16x8*)&lB[(wc * 64 + n * 16 + rbase) * 64 + kph];
    }
#pragma unroll
    for (int kk = 0; kk < 2; ++kk)
#pragma unroll
      for (int m = 0; m < 4; ++m)
#pragma unroll
        for (int n = 0; n < 4; ++n)
          acc[m][n] = __builtin_amdgcn_mfma_f32_16x16x32_bf16(
              af[kk][m], bfr[kk][n], acc[m][n], 0, 0, 0);
    __syncthreads();
  }

  const int baseRow = row0 + wr * 64 + ((lane >> 4) * 4);
  const int baseCol = col0 + wc * 64 + (lane & 15);
#pragma unroll
  for (int m = 0; m < 4; ++m) {
#pragma unroll
    for (int n = 0; n < 4; ++n) {
      const int colc = baseCol + n * 16;
      if (colc < N) {
        const float bv = bias ? bias[colc] : 0.f;
        const int rowc0 = baseRow + m * 16;
#pragma unroll
        for (int r = 0; r < 4; ++r) {
          float v = acc[m][n][r] + bv;
          if (outF) outF[(size_t)(rowc0 + r) * ldc + colc] = v;
          if (outB) outB[(size_t)(rowc0 + r) * ldc + colc] = f2bf(v);
        }
      }
    }
  }
}

// ---- GEMM 256x256, m201 8-phase template + T1 chunked XCD swizzle ----
// r15: staging rebalanced for latency cover. All 8 loads of tile t+2 are
// issued at P3 (A0) / P4 (A1,B0,B1) of iter t -- every load gets 5-6 phases
// of flight before its P1(t+2) consumer; boundary waits vmcnt(8) (drain tile
// t+1's 8, keep t+2's 8). WAR-safe: P3's trailing barrier confirms all LDS
// reads of buf d (af0@P1, af1@P2, bf01@P1, bf23@P3; Q4 reuses registers).
__global__ void __launch_bounds__(512, 2) gemm8p_k(
    const unsigned short* __restrict__ A, const unsigned short* __restrict__ Bt,
    const float* __restrict__ bias, float* __restrict__ outF,
    unsigned short* __restrict__ outB, unsigned short* __restrict__ vt,
    int M, int N, int K, int lda, int ldc, int relu) {
  __shared__ __align__(16) unsigned short lA[2][2][8192];
  __shared__ __align__(16) unsigned short lB[2][2][8192];
  const int tid = threadIdx.x;  // 0..511
  const int wv = tid >> 6, lane = tid & 63;

  int bx = blockIdx.x, by = blockIdx.y;
  {
    const int nwg = gridDim.x * gridDim.y;
    if ((nwg & 7) == 0) {
      int lin = by * gridDim.x + bx;
      lin = (lin & 7) * (nwg >> 3) + (lin >> 3);  // bijective, chunked
      by = lin / gridDim.x;
      bx = lin - by * gridDim.x;
    }
  }
  const int row0 = by * 256, col0 = bx * 256;
  const int wr = wv >> 2, wc = wv & 3;  // 2M x 4N; wave tile 128x64

  f32x4 acc[8][4] = {};

  const int sColSw = (((tid & 7) ^ ((tid >> 3) & 7))) * 8;
  const unsigned short* gA = A + (size_t)(row0 + (tid >> 3)) * lda + sColSw;
  const unsigned short* gB = Bt + (size_t)(col0 + (tid >> 3)) * lda + sColSw;
  const size_t step64 = (size_t)64 * lda;

  const int rbase = lane & 15;
  const int g8 = (lane >> 4) * 8;
  const int rsw = (rbase & 7) * 8;

  const int nt = K >> 6;

#define STGA(t, h)                                                       \
  {                                                                      \
    const unsigned short* s_ = gA + (size_t)(t) * 64 + (size_t)(2 * (h)) * step64; \
    gload_lds16(s_, &lA[(t) & 1][h][tid * 8]);                           \
    gload_lds16(s_ + step64, &lA[(t) & 1][h][4096 + tid * 8]);           \
  }
#define STGB(t, h)                                                       \
  {                                                                      \
    const unsigned short* s_ = gB + (size_t)(t) * 64 + (size_t)(2 * (h)) * step64; \
    gload_lds16(s_, &lB[(t) & 1][h][tid * 8]);                           \
    gload_lds16(s_ + step64, &lB[(t) & 1][h][4096 + tid * 8]);           \
  }

  // prologue: stage t0 and t1 completely (16 loads); wait t0 (oldest 8)
  STGA(0, 0); STGA(0, 1); STGB(0, 0); STGB(0, 1);
  STGA(1, 0); STGA(1, 1); STGB(1, 0); STGB(1, 1);
  asm volatile("s_waitcnt vmcnt(8)" ::: "memory");
  __builtin_amdgcn_s_barrier();

  for (int t = 0; t < nt; ++t) {
    const int d = t & 1;
    const unsigned short* lah = &lA[d][wr][0];
    const unsigned short* lbh = &lB[d][wc >> 1][0];
    const int bro = (wc & 1) * 64;
    s16x8 af0[4][2], af1[4][2], bf01[2][2], bf23[2][2];
    // ---- P1 (load-free) ----
#pragma unroll
    for (int ks = 0; ks < 2; ++ks) {
      const int kph = (ks * 32 + g8) ^ rsw;
#pragma unroll
      for (int m = 0; m < 4; ++m)
        af0[m][ks] = *(const s16x8*)&lah[(m * 16 + rbase) * 64 + kph];
#pragma unroll
      for (int n = 0; n < 2; ++n)
        bf01[n][ks] = *(const s16x8*)&lbh[(bro + n * 16 + rbase) * 64 + kph];
    }
    __builtin_amdgcn_s_barrier();
    asm volatile("s_waitcnt lgkmcnt(0)" ::: "memory");
    __builtin_amdgcn_s_setprio(1);
#pragma unroll
    for (int m = 0; m < 4; ++m)
#pragma unroll
      for (int n = 0; n < 2; ++n)
#pragma unroll
        for (int ks = 0; ks < 2; ++ks)
          acc[m][n] = __builtin_amdgcn_mfma_f32_16x16x32_bf16(
              af0[m][ks], bf01[n][ks], acc[m][n], 0, 0, 0);
    __builtin_amdgcn_s_setprio(0);
    __builtin_amdgcn_s_barrier();
    // ---- P2 ----
#pragma unroll
    for (int ks = 0; ks < 2; ++ks) {
      const int kph = (ks * 32 + g8) ^ rsw;
#pragma unroll
      for (int m = 0; m < 4; ++m)
        af1[m][ks] = *(const s16x8*)&lah[(64 + m * 16 + rbase) * 64 + kph];
    }
    __builtin_amdgcn_s_barrier();
    asm volatile("s_waitcnt lgkmcnt(0)" ::: "memory");
    __builtin_amdgcn_s_setprio(1);
#pragma unroll
    for (int m = 0; m < 4; ++m)
#pragma unroll
      for (int n = 0; n < 2; ++n)
#pragma unroll
        for (int ks = 0; ks < 2; ++ks)
          acc[4 + m][n] = __builtin_amdgcn_mfma_f32_16x16x32_bf16(
              af1[m][ks], bf01[n][ks], acc[4 + m][n], 0, 0, 0);
    __builtin_amdgcn_s_setprio(0);
    __builtin_amdgcn_s_barrier();
    // ---- P3: stage (t+2).A0 (A half-0 of buf d free after P1's reads;
    //      barrier-confirmed at P2's leading barrier) ----
#pragma unroll
    for (int ks = 0; ks < 2; ++ks) {
      const int kph = (ks * 32 + g8) ^ rsw;
#pragma unroll
      for (int n = 0; n < 2; ++n)
        bf23[n][ks] =
            *(const s16x8*)&lbh[(bro + 32 + n * 16 + rbase) * 64 + kph];
    }
    if (t + 2 < nt) STGA(t + 2, 0);
    __builtin_amdgcn_s_barrier();
    asm volatile("s_waitcnt lgkmcnt(0)" ::: "memory");
    __builtin_amdgcn_s_setprio(1);
#pragma unroll
    for (int m = 0; m < 4; ++m)
#pragma unroll
      for (int n = 0; n < 2; ++n)
#pragma unroll
        for (int ks = 0; ks < 2; ++ks)
          acc[m][2 + n] = __builtin_amdgcn_mfma_f32_16x16x32_bf16(
              af0[m][ks], bf23[n][ks], acc[m][2 + n], 0, 0, 0);
    __builtin_amdgcn_s_setprio(0);
    __builtin_amdgcn_s_barrier();
    // ---- P4: stage (t+2).A1, (t+2).B0, (t+2).B1 (all reads of buf d done
    //      by P3's trailing barrier; Q4 consumes registers only) ----
    if (t + 2 < nt) { STGA(t + 2, 1); STGB(t + 2, 0); STGB(t + 2, 1); }
    __builtin_amdgcn_s_setprio(1);
#pragma unroll
    for (int m = 0; m < 4; ++m)
#pragma unroll
      for (int n = 0; n < 2; ++n)
#pragma unroll
        for (int ks = 0; ks < 2; ++ks)
          acc[4 + m][2 + n] = __builtin_amdgcn_mfma_f32_16x16x32_bf16(
              af1[m][ks], bf23[n][ks], acc[4 + m][2 + n], 0, 0, 0);
    __builtin_amdgcn_s_setprio(0);
    // boundary: tile t+1 (8 oldest) must be landed; t+2's 8 stay in flight
    if (t + 2 < nt)
      asm volatile("s_waitcnt vmcnt(8)" ::: "memory");
    else if (t + 1 < nt)
      asm volatile("s_waitcnt vmcnt(0)" ::: "memory");
    __builtin_amdgcn_s_barrier();
  }
#undef STGA
#undef STGB

  const int baseRow = row0 + wr * 128 + ((lane >> 4) * 4);
  const int baseCol = col0 + wc * 64 + rbase;
#pragma unroll
  for (int m = 0; m < 8; ++m) {
#pragma unroll
    for (int n = 0; n < 4; ++n) {
      const int colc = baseCol + n * 16;
      if (colc < N) {
        const int rowc0 = baseRow + m * 16;
        if (vt && colc >= 2048) {
          const int f = colc - 2048;
          const int b = rowc0 >> 10, t0 = rowc0 & 1023;
          u16x4 o;
#pragma unroll
          for (int r = 0; r < 4; ++r) o[r] = f2bf(acc[m][n][r]);
          *(u16x4*)&vt[((size_t)((b << 4) + (f >> 6)) * 64 + (f & 63)) * 1024 + t0] = o;
        } else {
          const float bv = bias ? bias[colc] : 0.f;
#pragma unroll
          for (int r = 0; r < 4; ++r) {
            float v = acc[m][n][r] + bv;
            if (relu) v = fmaxf(v, 0.f);
            if (outF) outF[(size_t)(rowc0 + r) * ldc + colc] = v;
            if (outB) outB[(size_t)(rowc0 + r) * ldc + colc] = f2bf(v);
          }
        }
      }
    }
  }
}

// ------- fused causal attention: max-free softmax, 2 q-frags per wave ------
__global__ void __launch_bounds__(256) attn_k(const unsigned short* __restrict__ Q,
                                              const unsigned short* __restrict__ Kb,
                                              const unsigned short* __restrict__ Vt,
                                              unsigned short* __restrict__ O,
                                              int ldq) {
  const int bh = blockIdx.y;
  const int qt = (bh < 32) ? blockIdx.x : 7 - blockIdx.x;  // balanced remap
  const int b = bh >> 4, h = bh & 15;
  const int tid = threadIdx.x, wv = tid >> 6, lane = tid & 63;
  const int g = lane >> 4, c = lane & 15;
  __shared__ __align__(16) unsigned short lP[4][2][2][16 * 64];
  const int qb0 = qt * 128 + wv * 16;  // frag A rows
  const int qb1 = qb0 + 64;            // frag B rows
  s16x8 qfA0, qfA1, qfB0, qfB1;
  {
    const size_t qoffA = ((size_t)(b * 1024 + qb0 + c)) * ldq + h * 64 + g * 8;
    qfA0 = *(const s16x8*)&Q[qoffA];
    qfA1 = *(const s16x8*)&Q[qoffA + 32];
    const size_t qoffB = ((size_t)(b * 1024 + qb1 + c)) * ldq + h * 64 + g * 8;
    qfB0 = *(const s16x8*)&Q[qoffB];
    qfB1 = *(const s16x8*)&Q[qoffB + 32];
  }
  f32x4 accA[4] = {}, accB[4] = {};
  float lsumA[4] = {0.f, 0.f, 0.f, 0.f}, lsumB[4] = {0.f, 0.f, 0.f, 0.f};
  const float SC = 0.18033688011f;   // 0.125 * log2(e)
  const float SB = -5.77078016356f;  // -4 * log2(e)

  const int nt = 2 * qt + 2;
  for (int kt = 0; kt < nt; ++kt) {
    // modes: 0=full, 1=diagonal-mask, 2=skip
    const int modeA = (kt < nt - 2) ? 0 : ((kt == nt - 2) ? 1 : 2);
    const int modeB = (kt < nt - 1) ? 0 : 1;
    const int pb = kt & 1;
    unsigned short* lpA = &lP[wv][pb][0][0];
    unsigned short* lpB = &lP[wv][pb][1][0];
    float pA[4][4], pB[4][4];
#pragma unroll
    for (int n = 0; n < 4; ++n) {
      const size_t koff =
          ((size_t)(b * 1024 + kt * 64 + n * 16 + c)) * ldq + h * 64 + g * 8;
      s16x8 k0 = *(const s16x8*)&Kb[koff];
      s16x8 k1 = *(const s16x8*)&Kb[koff + 32];
      // ---- frag A ----
      if (modeA == 2 || (modeA == 1 && n > wv)) {
#pragma unroll
        for (int r = 0; r < 4; ++r) pA[n][r] = 0.f;
      } else {
        f32x4 s = {};
        s = __builtin_amdgcn_mfma_f32_16x16x32_bf16(qfA0, k0, s, 0, 0, 0);
        s = __builtin_amdgcn_mfma_f32_16x16x32_bf16(qfA1, k1, s, 0, 0, 0);
        if (modeA == 1 && n == wv) {
#pragma unroll
          for (int r = 0; r < 4; ++r) {
            const float e = (c > g * 4 + r) ? 0.f : exp2f(fmaf(s[r], SC, SB));
            pA[n][r] = e;
            lsumA[r] += e;
          }
        } else {
#pragma unroll
          for (int r = 0; r < 4; ++r) {
            const float e = exp2f(fmaf(s[r], SC, SB));
            pA[n][r] = e;
            lsumA[r] += e;
          }
        }
      }
      // ---- frag B ----
      if (modeB == 1 && n > wv) {
#pragma unroll
        for (int r = 0; r < 4; ++r) pB[n][r] = 0.f;
      } else {
        f32x4 s = {};
        s = __builtin_amdgcn_mfma_f32_16x16x32_bf16(qfB0, k0, s, 0, 0, 0);
        s = __builtin_amdgcn_mfma_f32_16x16x32_bf16(qfB1, k1, s, 0, 0, 0);
        if (modeB == 1 && n == wv) {
#pragma unroll
          for (int r = 0; r < 4; ++r) {
            const float e = (c > g * 4 + r) ? 0.f : exp2f(fmaf(s[r], SC, SB));
            pB[n][r] = e;
            lsumB[r] += e;
          }
        } else {
#pragma unroll
          for (int r = 0; r < 4; ++r) {
            const float e = exp2f(fmaf(s[r], SC, SB));
            pB[n][r] = e;
            lsumB[r] += e;
          }
        }
      }
    }
    // wave-private lP (row-major P[q16][key64]): no barriers needed
    if (modeA < 2) {
#pragma unroll
      for (int n = 0; n < 4; ++n)
#pragma unroll
        for (int r = 0; r < 4; ++r)
          lpA[(g * 4 + r) * 64 + n * 16 + c] = f2bf(pA[n][r]);
    }
#pragma unroll
    for (int n = 0; n < 4; ++n)
#pragma unroll
      for (int r = 0; r < 4; ++r)
        lpB[(g * 4 + r) * 64 + n * 16 + c] = f2bf(pB[n][r]);
    s16x8 paA0, paA1;
    if (modeA < 2) {
      paA0 = *(const s16x8*)&lpA[c * 64 + g * 8];
      paA1 = *(const s16x8*)&lpA[c * 64 + 32 + g * 8];
    }
    s16x8 paB0 = *(const s16x8*)&lpB[c * 64 + g * 8];
    s16x8 paB1 = *(const s16x8*)&lpB[c * 64 + 32 + g * 8];
#pragma unroll
    for (int n = 0; n < 4; ++n) {
      const size_t voff =
          ((size_t)(bh * 64 + n * 16 + c)) * 1024 + kt * 64 + g * 8;
      s16x8 v0 = *(const s16x8*)&Vt[voff];
      s16x8 v1 = *(const s16x8*)&Vt[voff + 32];
      if (modeA < 2) {
        accA[n] = __builtin_amdgcn_mfma_f32_16x16x32_bf16(paA0, v0, accA[n], 0, 0, 0);
        accA[n] = __builtin_amdgcn_mfma_f32_16x16x32_bf16(paA1, v1, accA[n], 0, 0, 0);
      }
      accB[n] = __builtin_amdgcn_mfma_f32_16x16x32_bf16(paB0, v0, accB[n], 0, 0, 0);
      accB[n] = __builtin_amdgcn_mfma_f32_16x16x32_bf16(paB1, v1, accB[n], 0, 0, 0);
    }
  }
  // deferred denominators: reduce over the 16 key-lanes (c), once per frag
  float invA[4], invB[4];
#pragma unroll
  for (int r = 0; r < 4; ++r) {
#pragma unroll
    for (int m = 1; m <= 8; m <<= 1) {
      lsumA[r] += __shfl_xor(lsumA[r], m);
      lsumB[r] += __shfl_xor(lsumB[r], m);
    }
    invA[r] = 1.f / lsumA[r];
    invB[r] = 1.f / lsumB[r];
  }
#pragma unroll
  for (int n = 0; n < 4; ++n)
#pragma unroll
    for (int r = 0; r < 4; ++r) {
      const size_t rowA = (size_t)(b * 1024 + qb0 + g * 4 + r);
      O[rowA * DM + h * 64 + n * 16 + c] = f2bf(accA[n][r] * invA[r]);
      const size_t rowB = (size_t)(b * 1024 + qb1 + g * 4 + r);
      O[rowB * DM + h * 64 + n * 16 + c] = f2bf(accB[n][r] * invB[r]);
    }
}

// ---------------- host ----------------
extern "C" void kernel_launch(void* const* d_in, const int* in_sizes, int n_in,
                              void* d_out, int out_size, void* d_ws, size_t ws_size,
                              hipStream_t stream) {
  const int* idx = (const int*)d_in[0];
  const float* wte = (const float*)d_in[1];
  const float* wpe = (const float*)d_in[2];
  const float* wq = (const float*)d_in[3];
  const float* wk = (const float*)d_in[4];
  const float* wv = (const float*)d_in[5];
  const float* wo = (const float*)d_in[6];
  const float* bo = (const float*)d_in[7];
  const float* ln1w = (const float*)d_in[8];
  const float* ln1b = (const float*)d_in[9];
  const float* ln2w = (const float*)d_in[10];
  const float* ln2b = (const float*)d_in[11];
  const float* w1 = (const float*)d_in[12];
  const float* b1 = (const float*)d_in[13];
  const float* w2 = (const float*)d_in[14];
  const float* b2 = (const float*)d_in[15];
  const float* lnfw = (const float*)d_in[16];
  const float* lnfb = (const float*)d_in[17];
  const float* wlm = (const float*)d_in[18];
  const float* blm = (const float*)d_in[19];
  float* out = (float*)d_out;

  char* ws = (char*)d_ws;
  size_t off = 0;
  auto alloc = [&](size_t bytes) -> void* {
    void* p = ws + off;
    off += (bytes + 255) & ~(size_t)255;
    return p;
  };
  unsigned short* wqkvT = (unsigned short*)alloc((size_t)NLAYER * 3072 * DM * 2);  // 48MB
  unsigned short* woT = (unsigned short*)alloc((size_t)NLAYER * DM * DM * 2);      // 16MB
  unsigned short* w1T = (unsigned short*)alloc((size_t)NLAYER * DM * DFF2 * 2);    // 64MB
  unsigned short* w2T = (unsigned short*)alloc((size_t)NLAYER * DM * DFF2 * 2);    // 64MB
  // wlmT aliases w1T+w2T (dead after layer loop): 50432*1024*2 = 103MB <= 128MB
  unsigned short* wlmT = w1T;
  float* X = (float*)alloc((size_t)NTOK * DM * 4);                                 // 16MB
  unsigned short* Hb = (unsigned short*)alloc((size_t)NTOK * DM * 2);              // 8MB
  // union region 32MB: {QKVb 24MB + Ab 8MB} early, {P0 16MB + P1 16MB} at w2
  char* uni = (char*)alloc((size_t)32 * 1024 * 1024);
  unsigned short* QKVb = (unsigned short*)uni;
  unsigned short* Ab = (unsigned short*)(uni + (size_t)24 * 1024 * 1024);
  float* P0 = (float*)uni;
  float* P1 = (float*)(uni + (size_t)16 * 1024 * 1024);
  unsigned short* VtB = (unsigned short*)alloc((size_t)NTOK * DM * 2);             // 8MB
  unsigned short* Mid = (unsigned short*)alloc((size_t)NTOK * DFF2 * 2);           // 32MB
  float* MidF = (float*)Mid;

  const size_t qkvStride = (size_t)3072 * DM;
  convT_k<<<dim3(16, 16, 8), 256, 0, stream>>>(wq, wqkvT, DM, DM, qkvStride);
  convT_k<<<dim3(16, 16, 8), 256, 0, stream>>>(wk, wqkvT + (size_t)1024 * DM, DM, DM, qkvStride);
  convT_k<<<dim3(16, 16, 8), 256, 0, stream>>>(wv, wqkvT + (size_t)2048 * DM, DM, DM, qkvStride);
  convT_k<<<dim3(16, 16, 8), 256, 0, stream>>>(wo, woT, DM, DM, (size_t)DM * DM);
  convT_k<<<dim3(64, 16, 8), 256, 0, stream>>>(w1, w1T, DM, DFF2, (size_t)DM * DFF2);
  convT_k<<<dim3(16, 64, 8), 256, 0, stream>>>(w2, w2T, DFF2, DM, (size_t)DM * DFF2);

  embed_k<<<dim3(NTOK), 256, 0, stream>>>(idx, wte, wpe, X);
  ln_k<<<dim3(NTOK), 256, 0, stream>>>(X, ln1w, ln1b, Hb);  // layer-0 ln1

  for (int i = 0; i < NLAYER; ++i) {
    const size_t wOff = (size_t)i * DM * DM;
    const size_t fOff = (size_t)i * DM * DFF2;
    // fused QKV (8-phase 256^2) with V-transpose epilogue
    gemm8p_k<<<dim3(12, 16), 512, 0, stream>>>(Hb, wqkvT + i * qkvStride,
                                               nullptr, nullptr, QKVb, VtB,
                                               NTOK, 3072, DM, DM, 3072, 0);
    attn_k<<<dim3(8, 64), 256, 0, stream>>>(QKVb, QKVb + 1024, VtB, Ab, 3072);
    // wo: split-K=2, partials into MidF (dead here)
    gemm_k<<<dim3(8, 32, 2), 256, 0, stream>>>(Ab, woT + wOff, nullptr, MidF,
                                               nullptr, NTOK, DM, DM / 2, DM, DM);
    reduce2ln_k<<<dim3(NTOK), 256, 0, stream>>>(X, bo + i * DM, MidF,
                                                MidF + (size_t)NTOK * DM,
                                                ln2w + i * DM, ln2b + i * DM, Hb);
    // w1: 8-phase 256^2, relu, bf16 out
    gemm8p_k<<<dim3(16, 16), 512, 0, stream>>>(Hb, w1T + fOff, b1 + i * DFF2,
                                               nullptr, Mid, nullptr, NTOK,
                                               DFF2, DM, DM, DFF2, 1);
    // w2: split-K=2, partials P0/P1 (union region, free)
    gemm_k<<<dim3(8, 32, 2), 256, 0, stream>>>(Mid, w2T + fOff, nullptr, P0,
                                               nullptr, NTOK, DM, DFF2 / 2,
                                               DFF2, DM);
    const float* nw = (i < NLAYER - 1) ? ln1w + (i + 1) * DM : lnfw;
    const float* nb = (i < NLAYER - 1) ? ln1b + (i + 1) * DM : lnfb;
    reduce2ln_k<<<dim3(NTOK), 256, 0, stream>>>(X, b2 + i * DM, P0, P1, nw, nb, Hb);
  }

  // LM head: convert wlm (padded rows alias dead w1T/w2T), 8-phase GEMM
  convT_k<<<dim3(788, 16, 1), 256, 0, stream>>>(wlm, wlmT, DM, NV, 0);
  gemm8p_k<<<dim3(197, 16), 512, 0, stream>>>(Hb, wlmT, blm, out, nullptr,
                                              nullptr, NTOK, NV, DM, DM, NV, 0);
}

// Round 17
// 2931.840 us; speedup vs baseline: 1.0053x; 1.0053x over previous
//
#include <hip/hip_runtime.h>
#include <cstdint>
#include <cstddef>

typedef __attribute__((ext_vector_type(4))) float f32x4;
typedef __attribute__((ext_vector_type(8))) short s16x8;
typedef __attribute__((ext_vector_type(4))) unsigned short u16x4;
typedef __attribute__((ext_vector_type(2))) unsigned short u16x2;

#define NLAYER 8
#define DM 1024
#define NTOK 4096
#define DFF2 4096
#define NV 50257

__device__ __forceinline__ unsigned short f2bf(float f) {
  unsigned int u = __float_as_uint(f);
  u = u + 0x7fffu + ((u >> 16) & 1u);
  return (unsigned short)(u >> 16);
}

// CK-style generic->AS1/AS3 conversion for global_load_lds (width 16B).
__device__ __forceinline__ void gload_lds16(const void* gp, void* lp) {
  const __attribute__((address_space(1))) unsigned int* g =
      reinterpret_cast<const __attribute__((address_space(1))) unsigned int*>(
          reinterpret_cast<uintptr_t>(gp));
  __attribute__((address_space(3))) unsigned int* l =
      reinterpret_cast<__attribute__((address_space(3))) unsigned int*>(
          (unsigned int)(uintptr_t)lp);
  __builtin_amdgcn_global_load_lds(g, l, 16, 0, 0);
}

// ---------------- weight convert + transpose: out[n][k] = bf16(in[k][n]) ----
__global__ void __launch_bounds__(256) convT_k(const float* __restrict__ in,
                                               unsigned short* __restrict__ out,
                                               int K, int N, size_t zStride) {
  __shared__ float tile[64][65];
  const int n0 = blockIdx.x * 64, k0 = blockIdx.y * 64;
  const float* inp = in + (size_t)blockIdx.z * K * N;
  unsigned short* outp = out + (size_t)blockIdx.z * zStride;
  const int tid = threadIdx.x;
#pragma unroll
  for (int p = 0; p < 16; ++p) {
    const int r = p * 4 + (tid >> 6);
    const int cc = tid & 63;
    const int gn = n0 + cc;
    tile[r][cc] = (gn < N) ? inp[(size_t)(k0 + r) * N + gn] : 0.f;
  }
  __syncthreads();
#pragma unroll
  for (int p = 0; p < 8; ++p) {
    const int lin = p * 256 + tid;
    const int rn = lin >> 5;
    const int c2 = (lin & 31) * 2;
    u16x2 o;
    o[0] = f2bf(tile[c2][rn]);
    o[1] = f2bf(tile[c2 + 1][rn]);
    *(u16x2*)&outp[(size_t)(n0 + rn) * K + k0 + c2] = o;
  }
}

// ---------------- embedding: x = wte[idx] + wpe[t] ----------------
__global__ void __launch_bounds__(256) embed_k(const int* __restrict__ idx,
                                               const float* __restrict__ wte,
                                               const float* __restrict__ wpe,
                                               float* __restrict__ X) {
  const int tok = blockIdx.x;
  const int t = tok & 1023;
  const int id = idx[tok];
  const int c = threadIdx.x * 4;
  f32x4 a = *(const f32x4*)&wte[(size_t)id * DM + c];
  f32x4 p = *(const f32x4*)&wpe[(size_t)t * DM + c];
  a = a + p;
  *(f32x4*)&X[(size_t)tok * DM + c] = a;
}

// ---------------- LayerNorm: f32 in -> bf16 out ----------------
__global__ void __launch_bounds__(256) ln_k(const float* __restrict__ X,
                                            const float* __restrict__ W,
                                            const float* __restrict__ Bp,
                                            unsigned short* __restrict__ O) {
  const int row = blockIdx.x, tid = threadIdx.x;
  const size_t base = (size_t)row * DM;
  f32x4 v = *(const f32x4*)&X[base + tid * 4];
  float s = v[0] + v[1] + v[2] + v[3];
  float q = v[0] * v[0] + v[1] * v[1] + v[2] * v[2] + v[3] * v[3];
#pragma unroll
  for (int m = 1; m < 64; m <<= 1) {
    s += __shfl_xor(s, m);
    q += __shfl_xor(q, m);
  }
  __shared__ float ps[4], pq[4];
  const int wv = tid >> 6;
  if ((tid & 63) == 0) { ps[wv] = s; pq[wv] = q; }
  __syncthreads();
  s = ps[0] + ps[1] + ps[2] + ps[3];
  q = pq[0] + pq[1] + pq[2] + pq[3];
  const float mu = s * (1.f / DM);
  const float var = q * (1.f / DM) - mu * mu;
  const float rstd = rsqrtf(var + 1e-5f);
  f32x4 w = *(const f32x4*)&W[tid * 4];
  f32x4 bb = *(const f32x4*)&Bp[tid * 4];
  u16x4 o;
#pragma unroll
  for (int j = 0; j < 4; ++j) o[j] = f2bf((v[j] - mu) * rstd * w[j] + bb[j]);
  *(u16x4*)&O[base + tid * 4] = o;
}

// -------- fused: X += bias + P0 + P1; then LN(X) -> bf16 O --------
__global__ void __launch_bounds__(256) reduce2ln_k(
    float* __restrict__ X, const float* __restrict__ bias,
    const float* __restrict__ P0, const float* __restrict__ P1,
    const float* __restrict__ W, const float* __restrict__ Bp,
    unsigned short* __restrict__ O) {
  const int row = blockIdx.x, tid = threadIdx.x;
  const size_t base = (size_t)row * DM;
  const size_t i = base + tid * 4;
  f32x4 v = *(f32x4*)&X[i];
  {
    f32x4 b = *(const f32x4*)&bias[tid * 4];
    f32x4 a = *(const f32x4*)&P0[i];
    f32x4 c = *(const f32x4*)&P1[i];
    v = v + b + a + c;
    *(f32x4*)&X[i] = v;
  }
  float s = v[0] + v[1] + v[2] + v[3];
  float q = v[0] * v[0] + v[1] * v[1] + v[2] * v[2] + v[3] * v[3];
#pragma unroll
  for (int m = 1; m < 64; m <<= 1) {
    s += __shfl_xor(s, m);
    q += __shfl_xor(q, m);
  }
  __shared__ float ps[4], pq[4];
  const int wv = tid >> 6;
  if ((tid & 63) == 0) { ps[wv] = s; pq[wv] = q; }
  __syncthreads();
  s = ps[0] + ps[1] + ps[2] + ps[3];
  q = pq[0] + pq[1] + pq[2] + pq[3];
  const float mu = s * (1.f / DM);
  const float var = q * (1.f / DM) - mu * mu;
  const float rstd = rsqrtf(var + 1e-5f);
  f32x4 w = *(const f32x4*)&W[tid * 4];
  f32x4 bb = *(const f32x4*)&Bp[tid * 4];
  u16x4 o;
#pragma unroll
  for (int j = 0; j < 4; ++j) o[j] = f2bf((v[j] - mu) * rstd * w[j] + bb[j]);
  *(u16x4*)&O[base + tid * 4] = o;
}

// ---------------- GEMM 128x128 (m97 structure, BK=64, XOR-swizzled LDS) ----
__global__ void __launch_bounds__(256) gemm_k(
    const unsigned short* __restrict__ A, const unsigned short* __restrict__ Bt,
    const float* __restrict__ bias, float* __restrict__ outF,
    unsigned short* __restrict__ outB, int M, int N, int K, int lda, int ldc) {
  __shared__ __align__(16) unsigned short lA[128 * 64];
  __shared__ __align__(16) unsigned short lB[128 * 64];
  const int tid = threadIdx.x;
  const int wv = tid >> 6, lane = tid & 63;
  const int row0 = blockIdx.y * 128, col0 = blockIdx.x * 128;
  const int wr = wv >> 1, wc = wv & 1;

  const int z = blockIdx.z;
  A += (size_t)z * K;
  Bt += (size_t)z * K;
  if (gridDim.z > 1) outF += (size_t)z * M * ldc;

  f32x4 acc[4][4] = {};

  const int sRow = tid >> 3;                              // 0..31
  const int sColSw = ((tid & 7) * 8) ^ ((sRow & 7) * 8);  // elements, [0,64)
  const unsigned short* gA = A + (size_t)(row0 + sRow) * lda + sColSw;
  const unsigned short* gB = Bt + (size_t)(col0 + sRow) * lda + sColSw;
  unsigned short* lAd = lA + tid * 8;
  unsigned short* lBd = lB + tid * 8;
  const size_t step32 = (size_t)32 * lda;

  const int rbase = lane & 15;
  const int kHi = (lane >> 4) * 8;
  const int kSw = (lane & 7) * 8;

  for (int kt = 0; kt < K; kt += 64) {
#pragma unroll
    for (int i = 0; i < 4; ++i) {
      gload_lds16(gA + kt + i * step32, lAd + i * 2048);
      gload_lds16(gB + kt + i * step32, lBd + i * 2048);
    }
    __syncthreads();
    s16x8 af[2][4], bfr[2][4];
#pragma unroll
    for (int kk = 0; kk < 2; ++kk) {
      const int kph = (kk * 32 + kHi) ^ kSw;
#pragma unroll
      for (int m = 0; m < 4; ++m)
        af[kk][m] = *(const s16x8*)&lA[(wr * 64 + m * 16 + rbase) * 64 + kph];
#pragma unroll
      for (int n = 0; n < 4; ++n)
        bfr[kk][n] = *(const s16x8*)&lB[(wc * 64 + n * 16 + rbase) * 64 + kph];
    }
#pragma unroll
    for (int kk = 0; kk < 2; ++kk)
#pragma unroll
      for (int m = 0; m < 4; ++m)
#pragma unroll
        for (int n = 0; n < 4; ++n)
          acc[m][n] = __builtin_amdgcn_mfma_f32_16x16x32_bf16(
              af[kk][m], bfr[kk][n], acc[m][n], 0, 0, 0);
    __syncthreads();
  }

  const int baseRow = row0 + wr * 64 + ((lane >> 4) * 4);
  const int baseCol = col0 + wc * 64 + (lane & 15);
#pragma unroll
  for (int m = 0; m < 4; ++m) {
#pragma unroll
    for (int n = 0; n < 4; ++n) {
      const int colc = baseCol + n * 16;
      if (colc < N) {
        const float bv = bias ? bias[colc] : 0.f;
        const int rowc0 = baseRow + m * 16;
#pragma unroll
        for (int r = 0; r < 4; ++r) {
          float v = acc[m][n][r] + bv;
          if (outF) outF[(size_t)(rowc0 + r) * ldc + colc] = v;
          if (outB) outB[(size_t)(rowc0 + r) * ldc + colc] = f2bf(v);
        }
      }
    }
  }
}

// ---- GEMM 256x256, m201 8-phase template (r8/r14 staging) + XCD swizzle ----
__global__ void __launch_bounds__(512, 2) gemm8p_k(
    const unsigned short* __restrict__ A, const unsigned short* __restrict__ Bt,
    const float* __restrict__ bias, float* __restrict__ outF,
    unsigned short* __restrict__ outB, unsigned short* __restrict__ vt,
    int M, int N, int K, int lda, int ldc, int relu) {
  __shared__ __align__(16) unsigned short lA[2][2][8192];
  __shared__ __align__(16) unsigned short lB[2][2][8192];
  const int tid = threadIdx.x;  // 0..511
  const int wv = tid >> 6, lane = tid & 63;

  int bx = blockIdx.x, by = blockIdx.y;
  {
    const int nwg = gridDim.x * gridDim.y;
    if ((nwg & 7) == 0) {
      int lin = by * gridDim.x + bx;
      lin = (lin & 7) * (nwg >> 3) + (lin >> 3);  // bijective, chunked
      by = lin / gridDim.x;
      bx = lin - by * gridDim.x;
    }
  }
  const int row0 = by * 256, col0 = bx * 256;
  const int wr = wv >> 2, wc = wv & 3;  // 2M x 4N; wave tile 128x64

  f32x4 acc[8][4] = {};

  const int sColSw = (((tid & 7) ^ ((tid >> 3) & 7))) * 8;
  const unsigned short* gA = A + (size_t)(row0 + (tid >> 3)) * lda + sColSw;
  const unsigned short* gB = Bt + (size_t)(col0 + (tid >> 3)) * lda + sColSw;
  const size_t step64 = (size_t)64 * lda;

  const int rbase = lane & 15;
  const int g8 = (lane >> 4) * 8;
  const int rsw = (rbase & 7) * 8;

  const int nt = K >> 6;

#define STGA(t, h)                                                       \
  {                                                                      \
    const unsigned short* s_ = gA + (size_t)(t) * 64 + (size_t)(2 * (h)) * step64; \
    gload_lds16(s_, &lA[(t) & 1][h][tid * 8]);                           \
    gload_lds16(s_ + step64, &lA[(t) & 1][h][4096 + tid * 8]);           \
  }
#define STGB(t, h)                                                       \
  {                                                                      \
    const unsigned short* s_ = gB + (size_t)(t) * 64 + (size_t)(2 * (h)) * step64; \
    gload_lds16(s_, &lB[(t) & 1][h][tid * 8]);                           \
    gload_lds16(s_ + step64, &lB[(t) & 1][h][4096 + tid * 8]);           \
  }

  STGA(0, 0); STGA(0, 1); STGB(0, 0); STGB(0, 1);
  STGA(1, 0); STGA(1, 1); STGB(1, 0);
  asm volatile("s_waitcnt vmcnt(6)" ::: "memory");
  __builtin_amdgcn_s_barrier();

  for (int t = 0; t < nt; ++t) {
    const int d = t & 1;
    const unsigned short* lah = &lA[d][wr][0];
    const unsigned short* lbh = &lB[d][wc >> 1][0];
    const int bro = (wc & 1) * 64;
    s16x8 af0[4][2], af1[4][2], bf01[2][2], bf23[2][2];
    // ---- P1 ----
#pragma unroll
    for (int ks = 0; ks < 2; ++ks) {
      const int kph = (ks * 32 + g8) ^ rsw;
#pragma unroll
      for (int m = 0; m < 4; ++m)
        af0[m][ks] = *(const s16x8*)&lah[(m * 16 + rbase) * 64 + kph];
#pragma unroll
      for (int n = 0; n < 2; ++n)
        bf01[n][ks] = *(const s16x8*)&lbh[(bro + n * 16 + rbase) * 64 + kph];
    }
    if (t + 1 < nt) STGB(t + 1, 1);
    __builtin_amdgcn_s_barrier();
    asm volatile("s_waitcnt lgkmcnt(0)" ::: "memory");
    __builtin_amdgcn_s_setprio(1);
#pragma unroll
    for (int m = 0; m < 4; ++m)
#pragma unroll
      for (int n = 0; n < 2; ++n)
#pragma unroll
        for (int ks = 0; ks < 2; ++ks)
          acc[m][n] = __builtin_amdgcn_mfma_f32_16x16x32_bf16(
              af0[m][ks], bf01[n][ks], acc[m][n], 0, 0, 0);
    __builtin_amdgcn_s_setprio(0);
    __builtin_amdgcn_s_barrier();
    // ---- P2 ----
#pragma unroll
    for (int ks = 0; ks < 2; ++ks) {
      const int kph = (ks * 32 + g8) ^ rsw;
#pragma unroll
      for (int m = 0; m < 4; ++m)
        af1[m][ks] = *(const s16x8*)&lah[(64 + m * 16 + rbase) * 64 + kph];
    }
    __builtin_amdgcn_s_barrier();
    asm volatile("s_waitcnt lgkmcnt(0)" ::: "memory");
    __builtin_amdgcn_s_setprio(1);
#pragma unroll
    for (int m = 0; m < 4; ++m)
#pragma unroll
      for (int n = 0; n < 2; ++n)
#pragma unroll
        for (int ks = 0; ks < 2; ++ks)
          acc[4 + m][n] = __builtin_amdgcn_mfma_f32_16x16x32_bf16(
              af1[m][ks], bf01[n][ks], acc[4 + m][n], 0, 0, 0);
    __builtin_amdgcn_s_setprio(0);
    __builtin_amdgcn_s_barrier();
    // ---- P3 ----
#pragma unroll
    for (int ks = 0; ks < 2; ++ks) {
      const int kph = (ks * 32 + g8) ^ rsw;
#pragma unroll
      for (int n = 0; n < 2; ++n)
        bf23[n][ks] =
            *(const s16x8*)&lbh[(bro + 32 + n * 16 + rbase) * 64 + kph];
    }
    if (t + 2 < nt) STGA(t + 2, 0);
    __builtin_amdgcn_s_barrier();
    asm volatile("s_waitcnt lgkmcnt(0)" ::: "memory");
    __builtin_amdgcn_s_setprio(1);
#pragma unroll
    for (int m = 0; m < 4; ++m)
#pragma unroll
      for (int n = 0; n < 2; ++n)
#pragma unroll
        for (int ks = 0; ks < 2; ++ks)
          acc[m][2 + n] = __builtin_amdgcn_mfma_f32_16x16x32_bf16(
              af0[m][ks], bf23[n][ks], acc[m][2 + n], 0, 0, 0);
    __builtin_amdgcn_s_setprio(0);
    __builtin_amdgcn_s_barrier();
    // ---- P4 ----
    if (t + 2 < nt) { STGA(t + 2, 1); STGB(t + 2, 0); }
    __builtin_amdgcn_s_setprio(1);
#pragma unroll
    for (int m = 0; m < 4; ++m)
#pragma unroll
      for (int n = 0; n < 2; ++n)
#pragma unroll
        for (int ks = 0; ks < 2; ++ks)
          acc[4 + m][2 + n] = __builtin_amdgcn_mfma_f32_16x16x32_bf16(
              af1[m][ks], bf23[n][ks], acc[4 + m][2 + n], 0, 0, 0);
    __builtin_amdgcn_s_setprio(0);
    if (t + 2 < nt)
      asm volatile("s_waitcnt vmcnt(6)" ::: "memory");
    else if (t + 1 < nt)
      asm volatile("s_waitcnt vmcnt(0)" ::: "memory");
    __builtin_amdgcn_s_barrier();
  }
#undef STGA
#undef STGB

  const int baseRow = row0 + wr * 128 + ((lane >> 4) * 4);
  const int baseCol = col0 + wc * 64 + rbase;
#pragma unroll
  for (int m = 0; m < 8; ++m) {
#pragma unroll
    for (int n = 0; n < 4; ++n) {
      const int colc = baseCol + n * 16;
      if (colc < N) {
        const int rowc0 = baseRow + m * 16;
        if (vt && colc >= 2048) {
          const int f = colc - 2048;
          const int b = rowc0 >> 10, t0 = rowc0 & 1023;
          u16x4 o;
#pragma unroll
          for (int r = 0; r < 4; ++r) o[r] = f2bf(acc[m][n][r]);
          *(u16x4*)&vt[((size_t)((b << 4) + (f >> 6)) * 64 + (f & 63)) * 1024 + t0] = o;
        } else {
          const float bv = bias ? bias[colc] : 0.f;
#pragma unroll
          for (int r = 0; r < 4; ++r) {
            float v = acc[m][n][r] + bv;
            if (relu) v = fmaxf(v, 0.f);
            if (outF) outF[(size_t)(rowc0 + r) * ldc + colc] = v;
            if (outB) outB[(size_t)(rowc0 + r) * ldc + colc] = f2bf(v);
          }
        }
      }
    }
  }
}

// ------- fused causal attention: max-free softmax, 2 q-frags per wave ------
__global__ void __launch_bounds__(256) attn_k(const unsigned short* __restrict__ Q,
                                              const unsigned short* __restrict__ Kb,
                                              const unsigned short* __restrict__ Vt,
                                              unsigned short* __restrict__ O,
                                              int ldq) {
  const int bh = blockIdx.y;
  const int qt = (bh < 32) ? blockIdx.x : 7 - blockIdx.x;  // balanced remap
  const int b = bh >> 4, h = bh & 15;
  const int tid = threadIdx.x, wv = tid >> 6, lane = tid & 63;
  const int g = lane >> 4, c = lane & 15;
  __shared__ __align__(16) unsigned short lP[4][2][2][16 * 64];
  const int qb0 = qt * 128 + wv * 16;  // frag A rows
  const int qb1 = qb0 + 64;            // frag B rows
  s16x8 qfA0, qfA1, qfB0, qfB1;
  {
    const size_t qoffA = ((size_t)(b * 1024 + qb0 + c)) * ldq + h * 64 + g * 8;
    qfA0 = *(const s16x8*)&Q[qoffA];
    qfA1 = *(const s16x8*)&Q[qoffA + 32];
    const size_t qoffB = ((size_t)(b * 1024 + qb1 + c)) * ldq + h * 64 + g * 8;
    qfB0 = *(const s16x8*)&Q[qoffB];
    qfB1 = *(const s16x8*)&Q[qoffB + 32];
  }
  f32x4 accA[4] = {}, accB[4] = {};
  float lsumA[4] = {0.f, 0.f, 0.f, 0.f}, lsumB[4] = {0.f, 0.f, 0.f, 0.f};
  const float SC = 0.18033688011f;   // 0.125 * log2(e)
  const float SB = -5.77078016356f;  // -4 * log2(e)

  const int nt = 2 * qt + 2;
  for (int kt = 0; kt < nt; ++kt) {
    // modes: 0=full, 1=diagonal-mask, 2=skip
    const int modeA = (kt < nt - 2) ? 0 : ((kt == nt - 2) ? 1 : 2);
    const int modeB = (kt < nt - 1) ? 0 : 1;
    const int pb = kt & 1;
    unsigned short* lpA = &lP[wv][pb][0][0];
    unsigned short* lpB = &lP[wv][pb][1][0];
    float pA[4][4], pB[4][4];
#pragma unroll
    for (int n = 0; n < 4; ++n) {
      const size_t koff =
          ((size_t)(b * 1024 + kt * 64 + n * 16 + c)) * ldq + h * 64 + g * 8;
      s16x8 k0 = *(const s16x8*)&Kb[koff];
      s16x8 k1 = *(const s16x8*)&Kb[koff + 32];
      // ---- frag A ----
      if (modeA == 2 || (modeA == 1 && n > wv)) {
#pragma unroll
        for (int r = 0; r < 4; ++r) pA[n][r] = 0.f;
      } else {
        f32x4 s = {};
        s = __builtin_amdgcn_mfma_f32_16x16x32_bf16(qfA0, k0, s, 0, 0, 0);
        s = __builtin_amdgcn_mfma_f32_16x16x32_bf16(qfA1, k1, s, 0, 0, 0);
        if (modeA == 1 && n == wv) {
#pragma unroll
          for (int r = 0; r < 4; ++r) {
            const float e = (c > g * 4 + r) ? 0.f : exp2f(fmaf(s[r], SC, SB));
            pA[n][r] = e;
            lsumA[r] += e;
          }
        } else {
#pragma unroll
          for (int r = 0; r < 4; ++r) {
            const float e = exp2f(fmaf(s[r], SC, SB));
            pA[n][r] = e;
            lsumA[r] += e;
          }
        }
      }
      // ---- frag B ----
      if (modeB == 1 && n > wv) {
#pragma unroll
        for (int r = 0; r < 4; ++r) pB[n][r] = 0.f;
      } else {
        f32x4 s = {};
        s = __builtin_amdgcn_mfma_f32_16x16x32_bf16(qfB0, k0, s, 0, 0, 0);
        s = __builtin_amdgcn_mfma_f32_16x16x32_bf16(qfB1, k1, s, 0, 0, 0);
        if (modeB == 1 && n == wv) {
#pragma unroll
          for (int r = 0; r < 4; ++r) {
            const float e = (c > g * 4 + r) ? 0.f : exp2f(fmaf(s[r], SC, SB));
            pB[n][r] = e;
            lsumB[r] += e;
          }
        } else {
#pragma unroll
          for (int r = 0; r < 4; ++r) {
            const float e = exp2f(fmaf(s[r], SC, SB));
            pB[n][r] = e;
            lsumB[r] += e;
          }
        }
      }
    }
    // wave-private lP (row-major P[q16][key64]): no barriers needed
    if (modeA < 2) {
#pragma unroll
      for (int n = 0; n < 4; ++n)
#pragma unroll
        for (int r = 0; r < 4; ++r)
          lpA[(g * 4 + r) * 64 + n * 16 + c] = f2bf(pA[n][r]);
    }
#pragma unroll
    for (int n = 0; n < 4; ++n)
#pragma unroll
      for (int r = 0; r < 4; ++r)
        lpB[(g * 4 + r) * 64 + n * 16 + c] = f2bf(pB[n][r]);
    s16x8 paA0, paA1;
    if (modeA < 2) {
      paA0 = *(const s16x8*)&lpA[c * 64 + g * 8];
      paA1 = *(const s16x8*)&lpA[c * 64 + 32 + g * 8];
    }
    s16x8 paB0 = *(const s16x8*)&lpB[c * 64 + g * 8];
    s16x8 paB1 = *(const s16x8*)&lpB[c * 64 + 32 + g * 8];
#pragma unroll
    for (int n = 0; n < 4; ++n) {
      const size_t voff =
          ((size_t)(bh * 64 + n * 16 + c)) * 1024 + kt * 64 + g * 8;
      s16x8 v0 = *(const s16x8*)&Vt[voff];
      s16x8 v1 = *(const s16x8*)&Vt[voff + 32];
      if (modeA < 2) {
        accA[n] = __builtin_amdgcn_mfma_f32_16x16x32_bf16(paA0, v0, accA[n], 0, 0, 0);
        accA[n] = __builtin_amdgcn_mfma_f32_16x16x32_bf16(paA1, v1, accA[n], 0, 0, 0);
      }
      accB[n] = __builtin_amdgcn_mfma_f32_16x16x32_bf16(paB0, v0, accB[n], 0, 0, 0);
      accB[n] = __builtin_amdgcn_mfma_f32_16x16x32_bf16(paB1, v1, accB[n], 0, 0, 0);
    }
  }
  // deferred denominators: reduce over the 16 key-lanes (c), once per frag
  float invA[4], invB[4];
#pragma unroll
  for (int r = 0; r < 4; ++r) {
#pragma unroll
    for (int m = 1; m <= 8; m <<= 1) {
      lsumA[r] += __shfl_xor(lsumA[r], m);
      lsumB[r] += __shfl_xor(lsumB[r], m);
    }
    invA[r] = 1.f / lsumA[r];
    invB[r] = 1.f / lsumB[r];
  }
#pragma unroll
  for (int n = 0; n < 4; ++n)
#pragma unroll
    for (int r = 0; r < 4; ++r) {
      const size_t rowA = (size_t)(b * 1024 + qb0 + g * 4 + r);
      O[rowA * DM + h * 64 + n * 16 + c] = f2bf(accA[n][r] * invA[r]);
      const size_t rowB = (size_t)(b * 1024 + qb1 + g * 4 + r);
      O[rowB * DM + h * 64 + n * 16 + c] = f2bf(accB[n][r] * invB[r]);
    }
}

// ---------------- host ----------------
extern "C" void kernel_launch(void* const* d_in, const int* in_sizes, int n_in,
                              void* d_out, int out_size, void* d_ws, size_t ws_size,
                              hipStream_t stream) {
  const int* idx = (const int*)d_in[0];
  const float* wte = (const float*)d_in[1];
  const float* wpe = (const float*)d_in[2];
  const float* wq = (const float*)d_in[3];
  const float* wk = (const float*)d_in[4];
  const float* wv = (const float*)d_in[5];
  const float* wo = (const float*)d_in[6];
  const float* bo = (const float*)d_in[7];
  const float* ln1w = (const float*)d_in[8];
  const float* ln1b = (const float*)d_in[9];
  const float* ln2w = (const float*)d_in[10];
  const float* ln2b = (const float*)d_in[11];
  const float* w1 = (const float*)d_in[12];
  const float* b1 = (const float*)d_in[13];
  const float* w2 = (const float*)d_in[14];
  const float* b2 = (const float*)d_in[15];
  const float* lnfw = (const float*)d_in[16];
  const float* lnfb = (const float*)d_in[17];
  const float* wlm = (const float*)d_in[18];
  const float* blm = (const float*)d_in[19];
  float* out = (float*)d_out;

  char* ws = (char*)d_ws;
  size_t off = 0;
  auto alloc = [&](size_t bytes) -> void* {
    void* p = ws + off;
    off += (bytes + 255) & ~(size_t)255;
    return p;
  };
  unsigned short* wqkvT = (unsigned short*)alloc((size_t)NLAYER * 3072 * DM * 2);  // 48MB
  unsigned short* woT = (unsigned short*)alloc((size_t)NLAYER * DM * DM * 2);      // 16MB
  unsigned short* w1T = (unsigned short*)alloc((size_t)NLAYER * DM * DFF2 * 2);    // 64MB
  unsigned short* w2T = (unsigned short*)alloc((size_t)NLAYER * DM * DFF2 * 2);    // 64MB
  // wlmT aliases w1T+w2T (dead after layer loop): 50432*1024*2 = 103MB <= 128MB
  unsigned short* wlmT = w1T;
  float* X = (float*)alloc((size_t)NTOK * DM * 4);                                 // 16MB
  unsigned short* Hb = (unsigned short*)alloc((size_t)NTOK * DM * 2);              // 8MB
  // union region 32MB: {QKVb 24MB + Ab 8MB} early, {P0 16MB + P1 16MB} at w2
  char* uni = (char*)alloc((size_t)32 * 1024 * 1024);
  unsigned short* QKVb = (unsigned short*)uni;
  unsigned short* Ab = (unsigned short*)(uni + (size_t)24 * 1024 * 1024);
  float* P0 = (float*)uni;
  float* P1 = (float*)(uni + (size_t)16 * 1024 * 1024);
  unsigned short* VtB = (unsigned short*)alloc((size_t)NTOK * DM * 2);             // 8MB
  unsigned short* Mid = (unsigned short*)alloc((size_t)NTOK * DFF2 * 2);           // 32MB
  float* MidF = (float*)Mid;

  const size_t qkvStride = (size_t)3072 * DM;
  convT_k<<<dim3(16, 16, 8), 256, 0, stream>>>(wq, wqkvT, DM, DM, qkvStride);
  convT_k<<<dim3(16, 16, 8), 256, 0, stream>>>(wk, wqkvT + (size_t)1024 * DM, DM, DM, qkvStride);
  convT_k<<<dim3(16, 16, 8), 256, 0, stream>>>(wv, wqkvT + (size_t)2048 * DM, DM, DM, qkvStride);
  convT_k<<<dim3(16, 16, 8), 256, 0, stream>>>(wo, woT, DM, DM, (size_t)DM * DM);
  convT_k<<<dim3(64, 16, 8), 256, 0, stream>>>(w1, w1T, DM, DFF2, (size_t)DM * DFF2);
  convT_k<<<dim3(16, 64, 8), 256, 0, stream>>>(w2, w2T, DFF2, DM, (size_t)DM * DFF2);

  embed_k<<<dim3(NTOK), 256, 0, stream>>>(idx, wte, wpe, X);
  ln_k<<<dim3(NTOK), 256, 0, stream>>>(X, ln1w, ln1b, Hb);  // layer-0 ln1

  for (int i = 0; i < NLAYER; ++i) {
    const size_t wOff = (size_t)i * DM * DM;
    const size_t fOff = (size_t)i * DM * DFF2;
    // fused QKV (8-phase 256^2) with V-transpose epilogue
    gemm8p_k<<<dim3(12, 16), 512, 0, stream>>>(Hb, wqkvT + i * qkvStride,
                                               nullptr, nullptr, QKVb, VtB,
                                               NTOK, 3072, DM, DM, 3072, 0);
    attn_k<<<dim3(8, 64), 256, 0, stream>>>(QKVb, QKVb + 1024, VtB, Ab, 3072);
    // wo: split-K=2, partials into MidF (dead here)
    gemm_k<<<dim3(8, 32, 2), 256, 0, stream>>>(Ab, woT + wOff, nullptr, MidF,
                                               nullptr, NTOK, DM, DM / 2, DM, DM);
    reduce2ln_k<<<dim3(NTOK), 256, 0, stream>>>(X, bo + i * DM, MidF,
                                                MidF + (size_t)NTOK * DM,
                                                ln2w + i * DM, ln2b + i * DM, Hb);
    // w1: 8-phase 256^2, relu, bf16 out
    gemm8p_k<<<dim3(16, 16), 512, 0, stream>>>(Hb, w1T + fOff, b1 + i * DFF2,
                                               nullptr, Mid, nullptr, NTOK,
                                               DFF2, DM, DM, DFF2, 1);
    // w2: split-K=2, partials P0/P1 (union region, free)
    gemm_k<<<dim3(8, 32, 2), 256, 0, stream>>>(Mid, w2T + fOff, nullptr, P0,
                                               nullptr, NTOK, DM, DFF2 / 2,
                                               DFF2, DM);
    const float* nw = (i < NLAYER - 1) ? ln1w + (i + 1) * DM : lnfw;
    const float* nb = (i < NLAYER - 1) ? ln1b + (i + 1) * DM : lnfb;
    reduce2ln_k<<<dim3(NTOK), 256, 0, stream>>>(X, b2 + i * DM, P0, P1, nw, nb, Hb);
  }

  // LM head: convert wlm (padded rows alias dead w1T/w2T), 8-phase GEMM
  convT_k<<<dim3(788, 16, 1), 256, 0, stream>>>(wlm, wlmT, DM, NV, 0);
  gemm8p_k<<<dim3(197, 16), 512, 0, stream>>>(Hb, wlmT, blm, out, nullptr,
                                              nullptr, NTOK, NV, DM, DM, NV, 0);
}